// Round 5
// baseline (394.315 us; speedup 1.0000x reference)
//
#include <hip/hip_runtime.h>
#include <hip/hip_bf16.h>

// B=1 T=64 W=88 HP=48 F0=53 HL=12 GATES=48 NU=24 NH=4 HD=6 K=25
// All float tensors are float32; condition is int32.
#define NPIX (64*88)          // 5632
#define NSEQ 88
#define TT 64
#define F0 53
#define GATES 48

__device__ __forceinline__ float sigm(float x){ return 1.0f/(1.0f+__expf(-x)); }
__device__ __forceinline__ float tanhfast(float x){ return 2.0f/(1.0f+__expf(-2.0f*x)) - 1.0f; }

// =================== D1: whole LSTM stack + qkv, one block per sequence ====
// block n = w-index; 256 threads (4 waves). LDS: sx 3392 + g 6144 + y0 1536
// + y1 1536 = 12608 floats = 50.4 KB (occupancy irrelevant: only 88 blocks).
__global__ __launch_bounds__(256) void k_lstm_fused(
    const float* __restrict__ feat, const int* __restrict__ cond,
    const float* __restrict__ mask, const float* __restrict__ emb,
    const float* __restrict__ wih0, const float* __restrict__ whh0,
    const float* __restrict__ bih0, const float* __restrict__ bhh0,
    const float* __restrict__ wih1, const float* __restrict__ whh1,
    const float* __restrict__ bih1, const float* __restrict__ bhh1,
    const float* __restrict__ qkv_w, const float* __restrict__ qkv_b,
    float* __restrict__ q, float* __restrict__ kh, float* __restrict__ vh){
  int n = blockIdx.x; int tid = threadIdx.x;
  int wave = tid >> 6; int lane = tid & 63;
  __shared__ float sx[TT*F0];     // x0 tile for this sequence
  __shared__ float g [2*TT*GATES];// gate pre-activations (reused L0/L1)
  __shared__ float y0[TT*24];     // layer-0 bidir output
  __shared__ float y1[TT*24];     // layer-1 bidir output

  // ---- stage x0 ----
  for (int idx = tid; idx < TT*F0; idx += 256){
    int t = idx / F0, f = idx - t*F0;
    float v;
    if (f < 48)      v = feat[(t*48 + f)*88 + n];
    else if (f < 52) v = emb[cond[t*88+n]*4 + (f-48)];
    else             v = mask[t*88+n];
    sx[idx] = v;
  }
  __syncthreads();

  // ---- gates layer 0 (len-53 dots) ----
  for (int idx = tid; idx < 2*TT*GATES; idx += 256){
    int j = idx % GATES; int r = idx / GATES; int t = r % TT; int d = r / TT;
    const float* wr = wih0 + (d*GATES + j)*F0;
    const float* xr = sx + t*F0;
    float acc = bih0[d*GATES+j] + bhh0[d*GATES+j];
    #pragma unroll 1
    for (int f=0; f<F0; ++f) acc += xr[f]*wr[f];
    g[(d*TT + t)*GATES + j] = acc;
  }
  __syncthreads();

  // ---- recurrence layer 0: wave d in {0,1} ----
  if (wave < 2){
    int d = wave;
    int jl = lane < GATES ? lane : 0;
    float w[12];
    #pragma unroll
    for (int m=0;m<12;++m) w[m] = whh0[(d*GATES+jl)*12+m];
    const float* gpb = g + d*TT*GATES;
    float hval = 0.f, cval = 0.f;
    int gl = lane < 12 ? lane : 0;
    int t0 = d ? (TT-1) : 0;
    float gnext = gpb[t0*GATES + jl];
    for (int s=0;s<TT;++s){
      int t = d ? (TT-1-s) : s;
      float gg = gnext;
      if (s+1 < TT){ int tn = d ? (TT-2-s) : (s+1); gnext = gpb[tn*GATES + jl]; }
      #pragma unroll
      for (int m=0;m<12;++m) gg += __shfl(hval, m) * w[m];
      float xi = __shfl(gg, gl);
      float xf = __shfl(gg, gl+12);
      float xg = __shfl(gg, gl+24);
      float xo = __shfl(gg, gl+36);
      float cn = sigm(xf)*cval + sigm(xi)*tanhfast(xg);
      float hn = sigm(xo)*tanhfast(cn);
      cval = cn; hval = hn;
      if (lane < 12) y0[t*24 + d*12 + lane] = hn;
    }
  }
  __syncthreads();

  // ---- gates layer 1 (len-24 dots) ----
  for (int idx = tid; idx < 2*TT*GATES; idx += 256){
    int j = idx % GATES; int r = idx / GATES; int t = r % TT; int d = r / TT;
    const float* wr = wih1 + (d*GATES + j)*24;
    const float* xr = y0 + t*24;
    float acc = bih1[d*GATES+j] + bhh1[d*GATES+j];
    #pragma unroll
    for (int c=0;c<24;++c) acc += xr[c]*wr[c];
    g[(d*TT + t)*GATES + j] = acc;
  }
  __syncthreads();

  // ---- recurrence layer 1 ----
  if (wave < 2){
    int d = wave;
    int jl = lane < GATES ? lane : 0;
    float w[12];
    #pragma unroll
    for (int m=0;m<12;++m) w[m] = whh1[(d*GATES+jl)*12+m];
    const float* gpb = g + d*TT*GATES;
    float hval = 0.f, cval = 0.f;
    int gl = lane < 12 ? lane : 0;
    int t0 = d ? (TT-1) : 0;
    float gnext = gpb[t0*GATES + jl];
    for (int s=0;s<TT;++s){
      int t = d ? (TT-1-s) : s;
      float gg = gnext;
      if (s+1 < TT){ int tn = d ? (TT-2-s) : (s+1); gnext = gpb[tn*GATES + jl]; }
      #pragma unroll
      for (int m=0;m<12;++m) gg += __shfl(hval, m) * w[m];
      float xi = __shfl(gg, gl);
      float xf = __shfl(gg, gl+12);
      float xg = __shfl(gg, gl+24);
      float xo = __shfl(gg, gl+36);
      float cn = sigm(xf)*cval + sigm(xi)*tanhfast(xg);
      float hn = sigm(xo)*tanhfast(cn);
      cval = cn; hval = hn;
      if (lane < 12) y1[t*24 + d*12 + lane] = hn;
    }
  }
  __syncthreads();

  // ---- qkv projection for this block's 64 pixels (p = t*88 + n) ----
  for (int idx = tid; idx < TT*72; idx += 256){
    int gq = idx % 72; int t = idx / 72;
    int p = t*88 + n;
    const float* xr = y1 + t*24;
    const float* wr = qkv_w + gq*24;
    float acc = qkv_b[gq];
    #pragma unroll
    for (int c=0;c<24;++c) acc += xr[c]*wr[c];
    int s = gq/24, rem = gq - s*24;
    if (s==0) q[p*24+rem] = acc*0.4082482904638631f;   // 1/sqrt(HD)
    else {
      int hh = rem/6, pos = rem - hh*6;
      float* dst = (s==1) ? kh : vh;
      size_t base = ((size_t)hh*NPIX + p)*8;
      dst[base + pos] = acc;
      if (pos < 2) dst[base + 6 + pos] = 0.f;   // zero pads (ws is poisoned)
    }
  }
}

// =================== D2/D3: attention + proj + tail, one block per pixel ===
// 4 waves, wave h = head h (R4's validated per-wave inner loop).
// last==0: tail = qkv -> q2/kh2/vh2.  last==1: tail = out head -> out.
__global__ __launch_bounds__(256) void k_attn_fused(
    const float* __restrict__ q, const float* __restrict__ kh,
    const float* __restrict__ vh, const float* __restrict__ rpb,
    const float* __restrict__ pw, const float* __restrict__ pb,
    const float* __restrict__ qkv_w, const float* __restrict__ qkv_b,
    float* __restrict__ q2, float* __restrict__ kh2, float* __restrict__ vh2,
    const float* __restrict__ ow, const float* __restrict__ ob,
    float* __restrict__ out, int last){
  int p = blockIdx.x; int tid = threadIdx.x;
  int h = tid >> 6; int lane = tid & 63;
  int i = p / 88, j = p - i*88;
  int si = min(max(i-12,0),39), sj = min(max(j-12,0),63);
  __shared__ float aorow[24];
  __shared__ float xrow[24];

  float qv[6];
  #pragma unroll
  for (int d=0; d<6; ++d) qv[d] = q[p*24 + h*6 + d];
  const float* kb = kh + (size_t)h*NPIX*8;
  const float* vb = vh + (size_t)h*NPIX*8;
  float lgv[10]; int roff[10];
  float lmax = -1e30f;
  #pragma unroll
  for (int it=0; it<10; ++it){
    int nb = lane + it*64;
    bool valid = nb < 625;
    int nbc = valid ? nb : 624;
    int a = nbc/25, cc = nbc - a*25;
    int gi = si + a, gj = sj + cc;
    int off = (gi*88+gj)*8;
    roff[it] = off;
    float4 k0 = *(const float4*)(kb + off);
    float4 k1 = *(const float4*)(kb + off + 4);
    float lg = qv[0]*k0.x+qv[1]*k0.y+qv[2]*k0.z+qv[3]*k0.w+qv[4]*k1.x+qv[5]*k1.y;
    lg += rpb[(h*49 + (gi - i + 24))*49 + (gj - j + 24)];
    lg = valid ? lg : -1e30f;
    lgv[it] = lg;
    lmax = fmaxf(lmax, lg);
  }
  #pragma unroll
  for (int off=32; off; off>>=1) lmax = fmaxf(lmax, __shfl_xor(lmax, off));
  float lsum = 0.f;
  #pragma unroll
  for (int it=0; it<10; ++it){
    float pe = __expf(lgv[it]-lmax);
    lgv[it] = pe; lsum += pe;
  }
  #pragma unroll
  for (int off=32; off; off>>=1) lsum += __shfl_xor(lsum, off);
  float acc[6] = {0,0,0,0,0,0};
  #pragma unroll
  for (int it=0; it<10; ++it){
    float4 v0 = *(const float4*)(vb + roff[it]);
    float4 v1 = *(const float4*)(vb + roff[it] + 4);
    float pe = lgv[it];
    acc[0] += pe*v0.x; acc[1] += pe*v0.y; acc[2] += pe*v0.z;
    acc[3] += pe*v0.w; acc[4] += pe*v1.x; acc[5] += pe*v1.y;
  }
  #pragma unroll
  for (int d=0; d<6; ++d){
    #pragma unroll
    for (int off=32; off; off>>=1) acc[d] += __shfl_xor(acc[d], off);
  }
  if (lane == 0){
    float inv = 1.f/lsum;
    #pragma unroll
    for (int d=0; d<6; ++d) aorow[h*6+d] = acc[d]*inv;
  }
  __syncthreads();

  // proj (24x24)
  if (tid < 24){
    float a2 = pb[tid];
    const float* wr = pw + tid*24;
    #pragma unroll
    for (int c=0;c<24;++c) a2 += aorow[c]*wr[c];
    xrow[tid] = a2;
  }
  __syncthreads();

  if (!last){
    if (tid < 72){
      float a2 = qkv_b[tid];
      const float* wr = qkv_w + tid*24;
      #pragma unroll
      for (int c=0;c<24;++c) a2 += xrow[c]*wr[c];
      int s = tid/24, rem = tid - s*24;
      if (s==0) q2[p*24+rem] = a2*0.4082482904638631f;
      else {
        int hh = rem/6, pos = rem - hh*6;
        float* dst = (s==1) ? kh2 : vh2;
        size_t base = ((size_t)hh*NPIX + p)*8;
        dst[base + pos] = a2;
        if (pos < 2) dst[base + 6 + pos] = 0.f;
      }
    }
  } else {
    if (tid < 5){
      float a2 = ob[tid];
      const float* wr = ow + tid*24;
      #pragma unroll
      for (int c=0;c<24;++c) a2 += xrow[c]*wr[c];
      out[p*5+tid] = a2;
    }
  }
}

extern "C" void kernel_launch(void* const* d_in, const int* in_sizes, int n_in,
                              void* d_out, int out_size, void* d_ws, size_t ws_size,
                              hipStream_t stream) {
  const float* feat    = (const float*)d_in[0];
  const int*   cond    = (const int*)  d_in[1];
  const float* mask    = (const float*)d_in[2];
  const float* emb     = (const float*)d_in[3];
  const float* w_ih_l0 = (const float*)d_in[4];
  const float* w_hh_l0 = (const float*)d_in[5];
  const float* b_ih_l0 = (const float*)d_in[6];
  const float* b_hh_l0 = (const float*)d_in[7];
  const float* w_ih_l1 = (const float*)d_in[8];
  const float* w_hh_l1 = (const float*)d_in[9];
  const float* b_ih_l1 = (const float*)d_in[10];
  const float* b_hh_l1 = (const float*)d_in[11];
  const float* qkv_w   = (const float*)d_in[12];
  const float* qkv_b   = (const float*)d_in[13];
  const float* rpb     = (const float*)d_in[14];
  const float* proj_w  = (const float*)d_in[15];
  const float* proj_b  = (const float*)d_in[16];
  const float* out_w   = (const float*)d_in[17];
  const float* out_b   = (const float*)d_in[18];
  float* out = (float*)d_out;

  float* ws  = (float*)d_ws;
  float* Q1  = ws;               // 135168
  float* KH1 = Q1  + 135168;     // 180224
  float* VH1 = KH1 + 180224;     // 180224
  float* Q2  = VH1 + 180224;     // 135168
  float* KH2 = Q2  + 135168;     // 180224
  float* VH2 = KH2 + 180224;     // 180224  (total ~3.9 MB)

  k_lstm_fused<<<NSEQ, 256, 0, stream>>>(
      feat, cond, mask, emb,
      w_ih_l0, w_hh_l0, b_ih_l0, b_hh_l0,
      w_ih_l1, w_hh_l1, b_ih_l1, b_hh_l1,
      qkv_w, qkv_b, Q1, KH1, VH1);

  k_attn_fused<<<NPIX, 256, 0, stream>>>(
      Q1, KH1, VH1, rpb, proj_w, proj_b, qkv_w, qkv_b,
      Q2, KH2, VH2, out_w, out_b, out, 0);

  k_attn_fused<<<NPIX, 256, 0, stream>>>(
      Q2, KH2, VH2, rpb, proj_w, proj_b, qkv_w, qkv_b,
      Q1, KH1, VH1, out_w, out_b, out, 1);
}

// Round 6
// 298.835 us; speedup vs baseline: 1.3195x; 1.3195x over previous
//
#include <hip/hip_runtime.h>
#include <hip/hip_bf16.h>

// B=1 T=64 W=88 HP=48 F0=53 HL=12 GATES=48 NU=24 NH=4 HD=6 K=25
// All float tensors are float32; condition is int32.
#define NPIX (64*88)          // 5632
#define NSEQ 88
#define TT 64
#define F0 53
#define GATES 48

__device__ __forceinline__ float sigm(float x){ return 1.0f/(1.0f+__expf(-x)); }
__device__ __forceinline__ float tanhfast(float x){ return 2.0f/(1.0f+__expf(-2.0f*x)) - 1.0f; }

// ============ D1: build x-tile + gates layer 0, whole-GPU parallel =========
// 704 blocks = (n, tc) with 8 timesteps each; x-tile AND weights in LDS.
__global__ __launch_bounds__(256) void k_gates0(
    const float* __restrict__ feat, const int* __restrict__ cond,
    const float* __restrict__ mask, const float* __restrict__ emb,
    const float* __restrict__ wih0, const float* __restrict__ bih0,
    const float* __restrict__ bhh0, float* __restrict__ gp){
  int n = blockIdx.x >> 3; int tc = blockIdx.x & 7; int t0 = tc*8;
  int tid = threadIdx.x;
  __shared__ float sx[8*F0];        // 424 floats
  __shared__ float sw[2*GATES*F0];  // 5088 floats (20 KB), stride 53 (coprime 32)

  for (int idx = tid; idx < 2*GATES*F0; idx += 256) sw[idx] = wih0[idx];
  for (int idx = tid; idx < 8*F0; idx += 256){
    int tl = idx / F0, f = idx - tl*F0; int t = t0 + tl;
    float v;
    if (f < 48)      v = feat[(t*48 + f)*88 + n];
    else if (f < 52) v = emb[cond[t*88+n]*4 + (f-48)];
    else             v = mask[t*88+n];
    sx[idx] = v;
  }
  __syncthreads();

  // 768 gate rows per block = 3 per thread; lanes have consecutive j.
  #pragma unroll
  for (int r = 0; r < 3; ++r){
    int row = tid + r*256;
    int d = row / 384; int rem = row - d*384;
    int tl = rem / 48; int j = rem - tl*48;
    const float* xr = sx + tl*F0;
    const float* wr = sw + (d*GATES + j)*F0;
    float a0=0.f, a1=0.f, a2=0.f, a3=0.f;
    #pragma unroll
    for (int f=0; f<52; f+=4){
      a0 += xr[f  ]*wr[f  ];
      a1 += xr[f+1]*wr[f+1];
      a2 += xr[f+2]*wr[f+2];
      a3 += xr[f+3]*wr[f+3];
    }
    float acc = bih0[d*GATES+j] + bhh0[d*GATES+j] + xr[52]*wr[52]
              + ((a0+a1)+(a2+a3));
    gp[((d*NSEQ + n)*TT + (t0+tl))*GATES + j] = acc;
  }
}

// ============ D2: serial core — rec0, gates1, rec1, qkv. 88 blocks ========
__global__ __launch_bounds__(256) void k_core(
    const float* __restrict__ gp, const float* __restrict__ whh0,
    const float* __restrict__ wih1, const float* __restrict__ bih1,
    const float* __restrict__ bhh1, const float* __restrict__ whh1,
    const float* __restrict__ qkv_w, const float* __restrict__ qkv_b,
    float* __restrict__ q, float* __restrict__ kh, float* __restrict__ vh){
  int n = blockIdx.x; int tid = threadIdx.x;
  int wave = tid >> 6; int lane = tid & 63;
  __shared__ float y0[TT*24];
  __shared__ float y1[TT*24];
  __shared__ float g1[2*TT*GATES];
  __shared__ float w1[2*GATES*25];   // wih1 padded stride 25 (bank-conflict-free)

  // waves 2,3 stage wih1 into LDS while waves 0,1 run recurrence 0
  if (wave >= 2){
    for (int idx = tid-128; idx < 2*GATES*24; idx += 128){
      int row = idx / 24, f = idx - row*24;
      w1[row*25 + f] = wih1[idx];
    }
  } else {
    int d = wave;
    int jl = lane < GATES ? lane : 0;
    float w[12];
    #pragma unroll
    for (int m=0;m<12;++m) w[m] = whh0[(d*GATES+jl)*12+m];
    const float* gpb = gp + (size_t)(d*NSEQ + n)*TT*GATES;
    float hval = 0.f, cval = 0.f;
    int gl = lane < 12 ? lane : 0;
    int t0 = d ? (TT-1) : 0;
    float gnext = gpb[t0*GATES + jl];
    for (int s=0;s<TT;++s){
      int t = d ? (TT-1-s) : s;
      float gg = gnext;
      if (s+1 < TT){ int tn = d ? (TT-2-s) : (s+1); gnext = gpb[tn*GATES + jl]; }
      #pragma unroll
      for (int m=0;m<12;++m) gg += __shfl(hval, m) * w[m];
      float xi = __shfl(gg, gl);
      float xf = __shfl(gg, gl+12);
      float xg = __shfl(gg, gl+24);
      float xo = __shfl(gg, gl+36);
      float cn = sigm(xf)*cval + sigm(xi)*tanhfast(xg);
      float hn = sigm(xo)*tanhfast(cn);
      cval = cn; hval = hn;
      if (lane < 12) y0[t*24 + d*12 + lane] = hn;
    }
  }
  __syncthreads();

  // gates layer 1: 6144 rows, 24 per thread, both operands LDS
  #pragma unroll
  for (int r = 0; r < 24; ++r){
    int row = tid + r*256;
    int d = row / 3072; int rem = row - d*3072;
    int t = rem / 48; int j = rem - t*48;
    const float* xr = y0 + t*24;
    const float* wr = w1 + (d*GATES + j)*25;
    float a0=0.f, a1=0.f;
    #pragma unroll
    for (int c=0; c<24; c+=2){ a0 += xr[c]*wr[c]; a1 += xr[c+1]*wr[c+1]; }
    g1[(d*TT + t)*GATES + j] = bih1[d*GATES+j] + bhh1[d*GATES+j] + a0 + a1;
  }
  __syncthreads();

  // recurrence layer 1 (waves 0,1)
  if (wave < 2){
    int d = wave;
    int jl = lane < GATES ? lane : 0;
    float w[12];
    #pragma unroll
    for (int m=0;m<12;++m) w[m] = whh1[(d*GATES+jl)*12+m];
    const float* gpb = g1 + d*TT*GATES;
    float hval = 0.f, cval = 0.f;
    int gl = lane < 12 ? lane : 0;
    for (int s=0;s<TT;++s){
      int t = d ? (TT-1-s) : s;
      float gg = gpb[t*GATES + jl];
      #pragma unroll
      for (int m=0;m<12;++m) gg += __shfl(hval, m) * w[m];
      float xi = __shfl(gg, gl);
      float xf = __shfl(gg, gl+12);
      float xg = __shfl(gg, gl+24);
      float xo = __shfl(gg, gl+36);
      float cn = sigm(xf)*cval + sigm(xi)*tanhfast(xg);
      float hn = sigm(xo)*tanhfast(cn);
      cval = cn; hval = hn;
      if (lane < 12) y1[t*24 + d*12 + lane] = hn;
    }
  }
  __syncthreads();

  // qkv projection for this sequence's 64 pixels (p = t*88 + n)
  #pragma unroll
  for (int r = 0; r < 18; ++r){
    int idx = tid + r*256;
    int gq = idx % 72; int t = idx / 72;
    int p = t*88 + n;
    const float* xr = y1 + t*24;
    const float* wr = qkv_w + gq*24;
    float a0=0.f, a1=0.f;
    #pragma unroll
    for (int c=0; c<24; c+=2){ a0 += xr[c]*wr[c]; a1 += xr[c+1]*wr[c+1]; }
    float acc = qkv_b[gq] + a0 + a1;
    int s = gq/24, rem = gq - s*24;
    if (s==0) q[p*24+rem] = acc*0.4082482904638631f;   // 1/sqrt(HD)
    else {
      int hh = rem/6, pos = rem - hh*6;
      float* dst = (s==1) ? kh : vh;
      size_t base = ((size_t)hh*NPIX + p)*8;
      dst[base + pos] = acc;
      if (pos < 2) dst[base + 6 + pos] = 0.f;   // zero pads (ws is poisoned)
    }
  }
}

// ============ D3/D4: attention + proj + tail, one block per pixel ==========
__global__ __launch_bounds__(256) void k_attn_fused(
    const float* __restrict__ q, const float* __restrict__ kh,
    const float* __restrict__ vh, const float* __restrict__ rpb,
    const float* __restrict__ pw, const float* __restrict__ pb,
    const float* __restrict__ qkv_w, const float* __restrict__ qkv_b,
    float* __restrict__ q2, float* __restrict__ kh2, float* __restrict__ vh2,
    const float* __restrict__ ow, const float* __restrict__ ob,
    float* __restrict__ out, int last){
  int p = blockIdx.x; int tid = threadIdx.x;
  int h = tid >> 6; int lane = tid & 63;
  int i = p / 88, j = p - i*88;
  int si = min(max(i-12,0),39), sj = min(max(j-12,0),63);
  __shared__ float aorow[24];
  __shared__ float xrow[24];

  float qv[6];
  #pragma unroll
  for (int d=0; d<6; ++d) qv[d] = q[p*24 + h*6 + d];
  const float* kb = kh + (size_t)h*NPIX*8;
  const float* vb = vh + (size_t)h*NPIX*8;
  float lgv[10]; int roff[10];
  float lmax = -1e30f;
  #pragma unroll
  for (int it=0; it<10; ++it){
    int nb = lane + it*64;
    bool valid = nb < 625;
    int nbc = valid ? nb : 624;
    int a = nbc/25, cc = nbc - a*25;
    int gi = si + a, gj = sj + cc;
    int off = (gi*88+gj)*8;
    roff[it] = off;
    float4 k0 = *(const float4*)(kb + off);
    float4 k1 = *(const float4*)(kb + off + 4);
    float lg = qv[0]*k0.x+qv[1]*k0.y+qv[2]*k0.z+qv[3]*k0.w+qv[4]*k1.x+qv[5]*k1.y;
    lg += rpb[(h*49 + (gi - i + 24))*49 + (gj - j + 24)];
    lg = valid ? lg : -1e30f;
    lgv[it] = lg;
    lmax = fmaxf(lmax, lg);
  }
  #pragma unroll
  for (int off=32; off; off>>=1) lmax = fmaxf(lmax, __shfl_xor(lmax, off));
  float lsum = 0.f;
  #pragma unroll
  for (int it=0; it<10; ++it){
    float pe = __expf(lgv[it]-lmax);
    lgv[it] = pe; lsum += pe;
  }
  #pragma unroll
  for (int off=32; off; off>>=1) lsum += __shfl_xor(lsum, off);
  float acc[6] = {0,0,0,0,0,0};
  #pragma unroll
  for (int it=0; it<10; ++it){
    float4 v0 = *(const float4*)(vb + roff[it]);
    float4 v1 = *(const float4*)(vb + roff[it] + 4);
    float pe = lgv[it];
    acc[0] += pe*v0.x; acc[1] += pe*v0.y; acc[2] += pe*v0.z;
    acc[3] += pe*v0.w; acc[4] += pe*v1.x; acc[5] += pe*v1.y;
  }
  #pragma unroll
  for (int d=0; d<6; ++d){
    #pragma unroll
    for (int off=32; off; off>>=1) acc[d] += __shfl_xor(acc[d], off);
  }
  if (lane == 0){
    float inv = 1.f/lsum;
    #pragma unroll
    for (int d=0; d<6; ++d) aorow[h*6+d] = acc[d]*inv;
  }
  __syncthreads();

  if (tid < 24){
    float a2 = pb[tid];
    const float* wr = pw + tid*24;
    #pragma unroll
    for (int c=0;c<24;++c) a2 += aorow[c]*wr[c];
    xrow[tid] = a2;
  }
  __syncthreads();

  if (!last){
    if (tid < 72){
      float a2 = qkv_b[tid];
      const float* wr = qkv_w + tid*24;
      #pragma unroll
      for (int c=0;c<24;++c) a2 += xrow[c]*wr[c];
      int s = tid/24, rem = tid - s*24;
      if (s==0) q2[p*24+rem] = a2*0.4082482904638631f;
      else {
        int hh = rem/6, pos = rem - hh*6;
        float* dst = (s==1) ? kh2 : vh2;
        size_t base = ((size_t)hh*NPIX + p)*8;
        dst[base + pos] = a2;
        if (pos < 2) dst[base + 6 + pos] = 0.f;
      }
    }
  } else {
    if (tid < 5){
      float a2 = ob[tid];
      const float* wr = ow + tid*24;
      #pragma unroll
      for (int c=0;c<24;++c) a2 += xrow[c]*wr[c];
      out[p*5+tid] = a2;
    }
  }
}

extern "C" void kernel_launch(void* const* d_in, const int* in_sizes, int n_in,
                              void* d_out, int out_size, void* d_ws, size_t ws_size,
                              hipStream_t stream) {
  const float* feat    = (const float*)d_in[0];
  const int*   cond    = (const int*)  d_in[1];
  const float* mask    = (const float*)d_in[2];
  const float* emb     = (const float*)d_in[3];
  const float* w_ih_l0 = (const float*)d_in[4];
  const float* w_hh_l0 = (const float*)d_in[5];
  const float* b_ih_l0 = (const float*)d_in[6];
  const float* b_hh_l0 = (const float*)d_in[7];
  const float* w_ih_l1 = (const float*)d_in[8];
  const float* w_hh_l1 = (const float*)d_in[9];
  const float* b_ih_l1 = (const float*)d_in[10];
  const float* b_hh_l1 = (const float*)d_in[11];
  const float* qkv_w   = (const float*)d_in[12];
  const float* qkv_b   = (const float*)d_in[13];
  const float* rpb     = (const float*)d_in[14];
  const float* proj_w  = (const float*)d_in[15];
  const float* proj_b  = (const float*)d_in[16];
  const float* out_w   = (const float*)d_in[17];
  const float* out_b   = (const float*)d_in[18];
  float* out = (float*)d_out;

  float* ws  = (float*)d_ws;
  float* GP  = ws;               // 2*88*64*48 = 540672
  float* Q1  = GP  + 540672;     // 135168
  float* KH1 = Q1  + 135168;     // 180224
  float* VH1 = KH1 + 180224;     // 180224
  float* Q2  = VH1 + 180224;     // 135168
  float* KH2 = Q2  + 135168;     // 180224
  float* VH2 = KH2 + 180224;     // 180224

  k_gates0<<<NSEQ*8, 256, 0, stream>>>(feat, cond, mask, emb,
      w_ih_l0, b_ih_l0, b_hh_l0, GP);

  k_core<<<NSEQ, 256, 0, stream>>>(GP, w_hh_l0,
      w_ih_l1, b_ih_l1, b_hh_l1, w_hh_l1, qkv_w, qkv_b, Q1, KH1, VH1);

  k_attn_fused<<<NPIX, 256, 0, stream>>>(
      Q1, KH1, VH1, rpb, proj_w, proj_b, qkv_w, qkv_b,
      Q2, KH2, VH2, out_w, out_b, out, 0);

  k_attn_fused<<<NPIX, 256, 0, stream>>>(
      Q2, KH2, VH2, rpb, proj_w, proj_b, qkv_w, qkv_b,
      Q1, KH1, VH1, out_w, out_b, out, 1);
}

// Round 7
// 223.199 us; speedup vs baseline: 1.7667x; 1.3389x over previous
//
#include <hip/hip_runtime.h>
#include <hip/hip_bf16.h>

// B=1 T=64 W=88 HP=48 F0=53 HL=12 GATES=48 NU=24 NH=4 HD=6 K=25
// All float tensors are float32; condition is int32.
#define NPIX (64*88)          // 5632
#define NSEQ 88
#define TT 64
#define F0 53
#define GATES 48

typedef __hip_bfloat16 bf16;
typedef unsigned short ushortT;

__device__ __forceinline__ float sigm(float x){ return 1.0f/(1.0f+__expf(-x)); }
__device__ __forceinline__ float tanhfast(float x){ return 2.0f/(1.0f+__expf(-2.0f*x)) - 1.0f; }

// unpack first 6 bf16 of a 16B row (uint4) to fp32
__device__ __forceinline__ void unpack6(uint4 r, float* f){
  f[0] = __uint_as_float(r.x << 16);
  f[1] = __uint_as_float(r.x & 0xffff0000u);
  f[2] = __uint_as_float(r.y << 16);
  f[3] = __uint_as_float(r.y & 0xffff0000u);
  f[4] = __uint_as_float(r.z << 16);
  f[5] = __uint_as_float(r.z & 0xffff0000u);
}

// ============ D1: build x-tile + gates layer 0, whole-GPU parallel =========
__global__ __launch_bounds__(256) void k_gates0(
    const float* __restrict__ feat, const int* __restrict__ cond,
    const float* __restrict__ mask, const float* __restrict__ emb,
    const float* __restrict__ wih0, const float* __restrict__ bih0,
    const float* __restrict__ bhh0, float* __restrict__ gp){
  int n = blockIdx.x >> 3; int tc = blockIdx.x & 7; int t0 = tc*8;
  int tid = threadIdx.x;
  __shared__ float sx[8*F0];
  __shared__ float sw[2*GATES*F0];  // stride 53 (coprime with 32 banks)

  for (int idx = tid; idx < 2*GATES*F0; idx += 256) sw[idx] = wih0[idx];
  for (int idx = tid; idx < 8*F0; idx += 256){
    int tl = idx / F0, f = idx - tl*F0; int t = t0 + tl;
    float v;
    if (f < 48)      v = feat[(t*48 + f)*88 + n];
    else if (f < 52) v = emb[cond[t*88+n]*4 + (f-48)];
    else             v = mask[t*88+n];
    sx[idx] = v;
  }
  __syncthreads();

  #pragma unroll
  for (int r = 0; r < 3; ++r){
    int row = tid + r*256;
    int d = row / 384; int rem = row - d*384;
    int tl = rem / 48; int j = rem - tl*48;
    const float* xr = sx + tl*F0;
    const float* wr = sw + (d*GATES + j)*F0;
    float a0=0.f, a1=0.f, a2=0.f, a3=0.f;
    #pragma unroll
    for (int f=0; f<52; f+=4){
      a0 += xr[f  ]*wr[f  ];
      a1 += xr[f+1]*wr[f+1];
      a2 += xr[f+2]*wr[f+2];
      a3 += xr[f+3]*wr[f+3];
    }
    float acc = bih0[d*GATES+j] + bhh0[d*GATES+j] + xr[52]*wr[52]
              + ((a0+a1)+(a2+a3));
    gp[((d*NSEQ + n)*TT + (t0+tl))*GATES + j] = acc;
  }
}

// ============ D2: serial core — rec0, gates1, rec1, qkv. 88 blocks ========
__global__ __launch_bounds__(256) void k_core(
    const float* __restrict__ gp, const float* __restrict__ whh0,
    const float* __restrict__ wih1, const float* __restrict__ bih1,
    const float* __restrict__ bhh1, const float* __restrict__ whh1,
    const float* __restrict__ qkv_w, const float* __restrict__ qkv_b,
    float* __restrict__ q, bf16* __restrict__ kh, bf16* __restrict__ vh){
  int n = blockIdx.x; int tid = threadIdx.x;
  int wave = tid >> 6; int lane = tid & 63;
  __shared__ float y0[TT*24];
  __shared__ float y1[TT*24];
  __shared__ float gbuf[2*TT*GATES];  // staged gp tile, later reused as g1
  __shared__ float w1[2*GATES*25];    // wih1 padded stride 25

  // ---- stage this sequence's gate tile (24 KB) into LDS, coalesced -------
  {
    const float4* src0 = (const float4*)(gp + (size_t)(0*NSEQ + n)*TT*GATES);
    const float4* src1 = (const float4*)(gp + (size_t)(1*NSEQ + n)*TT*GATES);
    float4* dst = (float4*)gbuf;
    for (int idx = tid; idx < TT*GATES/4; idx += 256){
      dst[idx] = src0[idx];
      dst[idx + TT*GATES/4] = src1[idx];
    }
  }
  // stage wih1 into LDS (padded)
  for (int idx = tid; idx < 2*GATES*24; idx += 256){
    int row = idx / 24, f = idx - row*24;
    w1[row*25 + f] = wih1[idx];
  }
  __syncthreads();

  // ---- recurrence layer 0: wave d in {0,1} -------------------------------
  if (wave < 2){
    int d = wave;
    int jl = lane < GATES ? lane : 0;
    float w[12];
    #pragma unroll
    for (int m=0;m<12;++m) w[m] = whh0[(d*GATES+jl)*12+m];
    const float* gpb = gbuf + d*TT*GATES;
    float hval = 0.f, cval = 0.f;
    int gl = lane < 12 ? lane : 0;
    for (int s=0;s<TT;++s){
      int t = d ? (TT-1-s) : s;
      float gg = gpb[t*GATES + jl];
      #pragma unroll
      for (int m=0;m<12;++m) gg += __shfl(hval, m) * w[m];
      float xi = __shfl(gg, gl);
      float xf = __shfl(gg, gl+12);
      float xg = __shfl(gg, gl+24);
      float xo = __shfl(gg, gl+36);
      float cn = sigm(xf)*cval + sigm(xi)*tanhfast(xg);
      float hn = sigm(xo)*tanhfast(cn);
      cval = cn; hval = hn;
      if (lane < 12) y0[t*24 + d*12 + lane] = hn;
    }
  }
  __syncthreads();

  // ---- gates layer 1 (overwrites gbuf; rec0 already consumed it) ---------
  #pragma unroll
  for (int r = 0; r < 24; ++r){
    int row = tid + r*256;
    int d = row / 3072; int rem = row - d*3072;
    int t = rem / 48; int j = rem - t*48;
    const float* xr = y0 + t*24;
    const float* wr = w1 + (d*GATES + j)*25;
    float a0=0.f, a1=0.f;
    #pragma unroll
    for (int c=0; c<24; c+=2){ a0 += xr[c]*wr[c]; a1 += xr[c+1]*wr[c+1]; }
    gbuf[(d*TT + t)*GATES + j] = bih1[d*GATES+j] + bhh1[d*GATES+j] + a0 + a1;
  }
  __syncthreads();

  // ---- recurrence layer 1 ------------------------------------------------
  if (wave < 2){
    int d = wave;
    int jl = lane < GATES ? lane : 0;
    float w[12];
    #pragma unroll
    for (int m=0;m<12;++m) w[m] = whh1[(d*GATES+jl)*12+m];
    const float* gpb = gbuf + d*TT*GATES;
    float hval = 0.f, cval = 0.f;
    int gl = lane < 12 ? lane : 0;
    for (int s=0;s<TT;++s){
      int t = d ? (TT-1-s) : s;
      float gg = gpb[t*GATES + jl];
      #pragma unroll
      for (int m=0;m<12;++m) gg += __shfl(hval, m) * w[m];
      float xi = __shfl(gg, gl);
      float xf = __shfl(gg, gl+12);
      float xg = __shfl(gg, gl+24);
      float xo = __shfl(gg, gl+36);
      float cn = sigm(xf)*cval + sigm(xi)*tanhfast(xg);
      float hn = sigm(xo)*tanhfast(cn);
      cval = cn; hval = hn;
      if (lane < 12) y1[t*24 + d*12 + lane] = hn;
    }
  }
  __syncthreads();

  // ---- qkv projection: q fp32, K/V bf16 rows of 8 (16 B) -----------------
  #pragma unroll
  for (int r = 0; r < 18; ++r){
    int idx = tid + r*256;
    int gq = idx % 72; int t = idx / 72;
    int p = t*88 + n;
    const float* xr = y1 + t*24;
    const float* wr = qkv_w + gq*24;
    float a0=0.f, a1=0.f;
    #pragma unroll
    for (int c=0; c<24; c+=2){ a0 += xr[c]*wr[c]; a1 += xr[c+1]*wr[c+1]; }
    float acc = qkv_b[gq] + a0 + a1;
    int s = gq/24, rem = gq - s*24;
    if (s==0) q[p*24+rem] = acc*0.4082482904638631f;   // 1/sqrt(HD)
    else {
      int hh = rem/6, pos = rem - hh*6;
      bf16* dst = (s==1) ? kh : vh;
      dst[((size_t)hh*NPIX + p)*8 + pos] = __float2bfloat16(acc);
      // pads (pos 6,7) are never read — no need to zero
    }
  }
}

// ============ D3/D4: attention + proj + tail, one block per pixel ==========
__global__ __launch_bounds__(256) void k_attn_fused(
    const float* __restrict__ q, const bf16* __restrict__ kh,
    const bf16* __restrict__ vh, const float* __restrict__ rpb,
    const float* __restrict__ pw, const float* __restrict__ pb,
    const float* __restrict__ qkv_w, const float* __restrict__ qkv_b,
    float* __restrict__ q2, bf16* __restrict__ kh2, bf16* __restrict__ vh2,
    const float* __restrict__ ow, const float* __restrict__ ob,
    float* __restrict__ out, int last){
  int p = blockIdx.x; int tid = threadIdx.x;
  int h = tid >> 6; int lane = tid & 63;
  int i = p / 88, j = p - i*88;
  int si = min(max(i-12,0),39), sj = min(max(j-12,0),63);
  __shared__ float aorow[24];
  __shared__ float xrow[24];

  float qv[6];
  #pragma unroll
  for (int d=0; d<6; ++d) qv[d] = q[p*24 + h*6 + d];
  const uint4* kb = (const uint4*)(kh + (size_t)h*NPIX*8);
  const uint4* vb = (const uint4*)(vh + (size_t)h*NPIX*8);
  float lgv[10]; int roff[10];
  float lmax = -1e30f;
  #pragma unroll
  for (int it=0; it<10; ++it){
    int nb = lane + it*64;
    bool valid = nb < 625;
    int nbc = valid ? nb : 624;
    int a = nbc/25, cc = nbc - a*25;
    int gi = si + a, gj = sj + cc;
    int row = gi*88+gj;
    roff[it] = row;
    float kr[6];
    unpack6(kb[row], kr);
    float lg = qv[0]*kr[0]+qv[1]*kr[1]+qv[2]*kr[2]+qv[3]*kr[3]+qv[4]*kr[4]+qv[5]*kr[5];
    lg += rpb[(h*49 + (gi - i + 24))*49 + (gj - j + 24)];
    lg = valid ? lg : -1e30f;
    lgv[it] = lg;
    lmax = fmaxf(lmax, lg);
  }
  #pragma unroll
  for (int off=32; off; off>>=1) lmax = fmaxf(lmax, __shfl_xor(lmax, off));
  float lsum = 0.f;
  #pragma unroll
  for (int it=0; it<10; ++it){
    float pe = __expf(lgv[it]-lmax);
    lgv[it] = pe; lsum += pe;
  }
  #pragma unroll
  for (int off=32; off; off>>=1) lsum += __shfl_xor(lsum, off);
  float acc[6] = {0,0,0,0,0,0};
  #pragma unroll
  for (int it=0; it<10; ++it){
    float vr[6];
    unpack6(vb[roff[it]], vr);
    float pe = lgv[it];
    #pragma unroll
    for (int d=0; d<6; ++d) acc[d] += pe*vr[d];
  }
  #pragma unroll
  for (int d=0; d<6; ++d){
    #pragma unroll
    for (int off=32; off; off>>=1) acc[d] += __shfl_xor(acc[d], off);
  }
  if (lane == 0){
    float inv = 1.f/lsum;
    #pragma unroll
    for (int d=0; d<6; ++d) aorow[h*6+d] = acc[d]*inv;
  }
  __syncthreads();

  if (tid < 24){
    float a2 = pb[tid];
    const float* wr = pw + tid*24;
    #pragma unroll
    for (int c=0;c<24;++c) a2 += aorow[c]*wr[c];
    xrow[tid] = a2;
  }
  __syncthreads();

  if (!last){
    if (tid < 72){
      float a2 = qkv_b[tid];
      const float* wr = qkv_w + tid*24;
      #pragma unroll
      for (int c=0;c<24;++c) a2 += xrow[c]*wr[c];
      int s = tid/24, rem = tid - s*24;
      if (s==0) q2[p*24+rem] = a2*0.4082482904638631f;
      else {
        int hh = rem/6, pos = rem - hh*6;
        bf16* dst = (s==1) ? kh2 : vh2;
        dst[((size_t)hh*NPIX + p)*8 + pos] = __float2bfloat16(a2);
      }
    }
  } else {
    if (tid < 5){
      float a2 = ob[tid];
      const float* wr = ow + tid*24;
      #pragma unroll
      for (int c=0;c<24;++c) a2 += xrow[c]*wr[c];
      out[p*5+tid] = a2;
    }
  }
}

extern "C" void kernel_launch(void* const* d_in, const int* in_sizes, int n_in,
                              void* d_out, int out_size, void* d_ws, size_t ws_size,
                              hipStream_t stream) {
  const float* feat    = (const float*)d_in[0];
  const int*   cond    = (const int*)  d_in[1];
  const float* mask    = (const float*)d_in[2];
  const float* emb     = (const float*)d_in[3];
  const float* w_ih_l0 = (const float*)d_in[4];
  const float* w_hh_l0 = (const float*)d_in[5];
  const float* b_ih_l0 = (const float*)d_in[6];
  const float* b_hh_l0 = (const float*)d_in[7];
  const float* w_ih_l1 = (const float*)d_in[8];
  const float* w_hh_l1 = (const float*)d_in[9];
  const float* b_ih_l1 = (const float*)d_in[10];
  const float* b_hh_l1 = (const float*)d_in[11];
  const float* qkv_w   = (const float*)d_in[12];
  const float* qkv_b   = (const float*)d_in[13];
  const float* rpb     = (const float*)d_in[14];
  const float* proj_w  = (const float*)d_in[15];
  const float* proj_b  = (const float*)d_in[16];
  const float* out_w   = (const float*)d_in[17];
  const float* out_b   = (const float*)d_in[18];
  float* out = (float*)d_out;

  float* ws  = (float*)d_ws;
  float* GP  = ws;               // 540672 floats
  float* Q1  = GP  + 540672;     // 135168
  float* Q2  = Q1  + 135168;     // 135168
  bf16*  KH1 = (bf16*)(Q2 + 135168);  // 4*5632*8 bf16 = 180224 halves (16B-aligned)
  bf16*  VH1 = KH1 + 180224;
  bf16*  KH2 = VH1 + 180224;
  bf16*  VH2 = KH2 + 180224;     // total ~4.7 MB

  k_gates0<<<NSEQ*8, 256, 0, stream>>>(feat, cond, mask, emb,
      w_ih_l0, b_ih_l0, b_hh_l0, GP);

  k_core<<<NSEQ, 256, 0, stream>>>(GP, w_hh_l0,
      w_ih_l1, b_ih_l1, b_hh_l1, w_hh_l1, qkv_w, qkv_b, Q1, KH1, VH1);

  k_attn_fused<<<NPIX, 256, 0, stream>>>(
      Q1, KH1, VH1, rpb, proj_w, proj_b, qkv_w, qkv_b,
      Q2, KH2, VH2, out_w, out_b, out, 0);

  k_attn_fused<<<NPIX, 256, 0, stream>>>(
      Q2, KH2, VH2, rpb, proj_w, proj_b, qkv_w, qkv_b,
      Q1, KH1, VH1, out_w, out_b, out, 1);
}